// Round 9
// baseline (200.105 us; speedup 1.0000x reference)
//
#include <hip/hip_runtime.h>
#include <math.h>

#define T_SEQ 2048
#define NH 16
#define HD 64
#define CEMB 1024
#define NEGINF -3.0e38f
#define LOG2E 1.4426950408889634f

typedef unsigned short ushort;
typedef unsigned int uint;
typedef __attribute__((ext_vector_type(8))) short short8;
typedef __attribute__((ext_vector_type(4))) float f32x4;

#if __has_builtin(__builtin_amdgcn_exp2f)
#define EXP2(x) __builtin_amdgcn_exp2f(x)
#else
#define EXP2(x) exp2f(x)
#endif

__device__ __forceinline__ float b2f(ushort h) {
    union { uint u; float f; } cv; cv.u = ((uint)h) << 16; return cv.f;
}
__device__ __forceinline__ ushort f2b(float f) {
    union { float f; uint u; } cv; cv.f = f;
    return (ushort)((cv.u + 0x7FFF + ((cv.u >> 16) & 1)) >> 16);
}
__device__ __forceinline__ ushort f2b_fast(float f) {   // round-half-up, 2 ops
    union { float f; uint u; } cv; cv.f = f;
    return (ushort)((cv.u + 0x8000) >> 16);
}
// pack two f32 -> packed bf16 pair (round-half-up) with one v_perm_b32
__device__ __forceinline__ uint pack_bf16(float a, float b) {
    union { float f; uint u; } ua, ub; ua.f = a; ub.f = b;
    return __builtin_amdgcn_perm(ub.u + 0x8000u, ua.u + 0x8000u, 0x07060302u);
}
__device__ __forceinline__ void gl2lds16(const ushort* g, ushort* l) {
    __builtin_amdgcn_global_load_lds(
        (const __attribute__((address_space(1))) void*)g,
        (__attribute__((address_space(3))) void*)l, 16, 0, 0);
}

// ---------------------------------------------------------------------------
// prep: merged f32->bf16 convert for x/Wqkv/Wproj + Wlow rows + bias_pre.
// ---------------------------------------------------------------------------
__global__ __launch_bounds__(256) void prep_kernel(
    const float* __restrict__ x, const float* __restrict__ Wqkv,
    const float* __restrict__ Wproj, const float* __restrict__ W_recip,
    const float* __restrict__ w_disc, const float* __restrict__ d_bias,
    ushort* __restrict__ xb, ushort* __restrict__ wqkvb,
    ushort* __restrict__ wprojb, float* __restrict__ bias_pre)
{
    const int bid = blockIdx.x;
    if (bid < 8192) {
        const float* src; ushort* dst; int off;
        if (bid < 4096)      { src = x;     dst = xb;     off = bid; }
        else if (bid < 7168) { src = Wqkv;  dst = wqkvb;  off = bid - 4096; }
        else                 { src = Wproj; dst = wprojb; off = bid - 7168; }
        const int i = (off * 256 + threadIdx.x) * 4;
        const float4 v = *(const float4*)&src[i];
        ushort4 o;
        o.x = f2b(v.x); o.y = f2b(v.y); o.z = f2b(v.z); o.w = f2b(v.w);
        *(ushort4*)&dst[i] = o;
        return;
    }
    if (bid >= 8224) {
        const int h = bid - 8224;
        const float wd = w_disc[h] * LOG2E;
        const int j = h * T_SEQ + threadIdx.x * 8;
        const float4 a = *(const float4*)&d_bias[j];
        const float4 c = *(const float4*)&d_bias[j + 4];
        float4 oa, oc;
        oa.x = a.x * wd; oa.y = a.y * wd; oa.z = a.z * wd; oa.w = a.w * wd;
        oc.x = c.x * wd; oc.y = c.y * wd; oc.z = c.z * wd; oc.w = c.w * wd;
        *(float4*)&bias_pre[j] = oa;
        *(float4*)&bias_pre[j + 4] = oc;
        return;
    }
    const int wb = bid - 8192;
    const int qk = wb >> 4, h = wb & 15;
    const int e0 = threadIdx.x * 4;
    f32x4 acc[8];
    #pragma unroll
    for (int r = 0; r < 8; ++r) acc[r] = (f32x4){0.f, 0.f, 0.f, 0.f};
    #pragma unroll 4
    for (int d = 0; d < 64; ++d) {
        const float4 xv = *(const float4*)&Wqkv[(size_t)(qk * 1024 + h * 64 + d) * 1024 + e0];
        #pragma unroll
        for (int r = 0; r < 8; ++r) {
            const float w = W_recip[d * 8 + r];
            acc[r][0] = fmaf(w, xv.x, acc[r][0]);
            acc[r][1] = fmaf(w, xv.y, acc[r][1]);
            acc[r][2] = fmaf(w, xv.z, acc[r][2]);
            acc[r][3] = fmaf(w, xv.w, acc[r][3]);
        }
    }
    #pragma unroll
    for (int r = 0; r < 8; ++r) {
        ushort4 o;
        o.x = f2b(acc[r][0]); o.y = f2b(acc[r][1]);
        o.z = f2b(acc[r][2]); o.w = f2b(acc[r][3]);
        *(ushort4*)&wqkvb[(size_t)(3072 + qk * 128 + h * 8 + r) * 1024 + e0] = o;
    }
}

// ---------------------------------------------------------------------------
// bf16 MFMA GEMM core (128x128 tile, BK=64, 4 waves, global_load_lds staging,
// XOR-swizzled LDS both sides).
// ---------------------------------------------------------------------------
#define GEMM_CORE(Aptr, Bptr, KDIM, SMEMN)                                     \
    __shared__ __align__(16) ushort SMEM[SMEMN];                               \
    ushort* const Asl = SMEM;                                                  \
    ushort* const Bsl = SMEM + 8192;                                           \
    const int row0 = blockIdx.x * 128;                                         \
    const int col0 = blockIdx.y * 128;                                         \
    const int tid = threadIdx.x;                                               \
    const int wave = tid >> 6, lane = tid & 63;                                \
    const int wm = wave >> 1, wn = wave & 1;                                   \
    const int quad = lane >> 4, lq = lane & 15;                                \
    const int l7 = lq & 7;                                                     \
    f32x4 acc[4][4];                                                           \
    _Pragma("unroll") for (int i = 0; i < 4; ++i)                              \
        _Pragma("unroll") for (int j = 0; j < 4; ++j)                          \
            acc[i][j] = (f32x4){0.f, 0.f, 0.f, 0.f};                           \
    for (int k0 = 0; k0 < (KDIM); k0 += 64) {                                  \
        _Pragma("unroll") for (int p = 0; p < 4; ++p) {                        \
            const int idx = p * 256 + tid;                                     \
            const int row = idx >> 3, slot = idx & 7;                          \
            const int kc = (slot ^ (row & 7)) << 3;                            \
            gl2lds16(&(Aptr)[(size_t)(row0 + row) * (KDIM) + k0 + kc], &Asl[idx * 8]); \
            gl2lds16(&(Bptr)[(size_t)(col0 + row) * (KDIM) + k0 + kc], &Bsl[idx * 8]); \
        }                                                                      \
        __syncthreads();                                                       \
        _Pragma("unroll") for (int ks = 0; ks < 2; ++ks) {                     \
            short8 af[4], bf[4];                                               \
            _Pragma("unroll") for (int i = 0; i < 4; ++i)                      \
                af[i] = *(const short8*)&Asl[(wm * 64 + i * 16 + lq) * 64 +    \
                                             (((ks * 4 + quad) ^ l7) << 3)];   \
            _Pragma("unroll") for (int j = 0; j < 4; ++j)                      \
                bf[j] = *(const short8*)&Bsl[(wn * 64 + j * 16 + lq) * 64 +    \
                                             (((ks * 4 + quad) ^ l7) << 3)];   \
            _Pragma("unroll") for (int i = 0; i < 4; ++i)                      \
                _Pragma("unroll") for (int j = 0; j < 4; ++j)                  \
                    acc[i][j] = __builtin_amdgcn_mfma_f32_16x16x32_bf16(       \
                        af[i], bf[j], acc[i][j], 0, 0, 0);                     \
        }                                                                      \
        __syncthreads();                                                       \
    }

// Kernel 1: extended qkv GEMM, N=3328. Epilogue Cs stride = 144 ushort
// (288B -> row-to-row bank step 8; the 4 quad-rows of each store hit
// disjoint 8-bank groups -> kills the 3.48M epilogue bank conflicts).
#define CSTR 144
__global__ __launch_bounds__(256, 4) void gemm_qkv_kernel(
    const ushort* __restrict__ A, const ushort* __restrict__ Bt,
    const float* __restrict__ w_std, const float* __restrict__ w_rec,
    ushort* __restrict__ qh, ushort* __restrict__ kh, ushort* __restrict__ vt)
{
    GEMM_CORE(A, Bt, 1024, 128 * CSTR)
    ushort* const Cs = SMEM;   // epilogue staging, overlays Asl/Bsl (safe)

    if (col0 >= 2048 && col0 < 3072) {
        #pragma unroll
        for (int j = 0; j < 4; ++j) {
            const int cc = col0 + wn * 64 + j * 16 + lq;
            const int h = (cc >> 6) & 15;
            const int d = cc & 63;
            #pragma unroll
            for (int i = 0; i < 4; ++i) {
                const int rr0 = row0 + wm * 64 + i * 16 + quad * 4;
                const int b = rr0 >> 11, t0 = rr0 & 2047;
                ushort4 pv;
                pv.x = f2b(acc[i][j][0]); pv.y = f2b(acc[i][j][1]);
                pv.z = f2b(acc[i][j][2]); pv.w = f2b(acc[i][j][3]);
                *(ushort4*)&vt[((((size_t)b * NH + h) * HD + d) * T_SEQ + t0)] = pv;
            }
        }
    } else if (col0 < 2048) {
        const bool isq = (col0 < 1024);
        #pragma unroll
        for (int j = 0; j < 4; ++j) {
            const int colc = wn * 64 + j * 16 + lq;
            const int h = ((col0 + colc) >> 6) & 15;
            const float sc = isq ? w_std[h] * (0.125f * LOG2E) : 1.0f;
            #pragma unroll
            for (int i = 0; i < 4; ++i)
                #pragma unroll
                for (int r = 0; r < 4; ++r)
                    Cs[(wm * 64 + i * 16 + quad * 4 + r) * CSTR + colc] =
                        f2b(acc[i][j][r] * sc);
        }
        __syncthreads();
        ushort* dst = isq ? qh : kh;
        const int hbase = (col0 >> 6) & 15;
        #pragma unroll
        for (int rep = 0; rep < 8; ++rep) {
            const int id = rep * 256 + tid;
            const int row = id >> 4, chunk = id & 15;
            if ((chunk & 7) == 7) continue;   // d=56..63 owned by tail blocks
            const int h = hbase + (chunk >> 3);
            const int d = (chunk & 7) * 8;
            const int rr = row0 + row;
            const int b = rr >> 11, t = rr & 2047;
            const uint4 val = *(const uint4*)&Cs[row * CSTR + chunk * 8];
            *(uint4*)&dst[((((size_t)b * NH + h) * T_SEQ + t) * HD + d)] = val;
        }
    } else {
        const bool isqlow = (col0 < 3200);
        #pragma unroll
        for (int j = 0; j < 4; ++j) {
            const int colc = wn * 64 + j * 16 + lq;
            const int h = colc >> 3;
            const float sc = isqlow ? 1.0f : w_rec[h] * (0.125f * LOG2E);
            #pragma unroll
            for (int i = 0; i < 4; ++i)
                #pragma unroll
                for (int r = 0; r < 4; ++r)
                    Cs[(wm * 64 + i * 16 + quad * 4 + r) * CSTR + colc] =
                        f2b(acc[i][j][r] * sc);
        }
        __syncthreads();
        ushort* dst = isqlow ? kh : qh;
        #pragma unroll
        for (int rep = 0; rep < 8; ++rep) {
            const int id = rep * 256 + tid;
            const int row = id >> 4, h = id & 15;
            const int rr = row0 + row;
            const int b = rr >> 11, t = rr & 2047;
            const uint4 val = *(const uint4*)&Cs[row * CSTR + h * 8];
            *(uint4*)&dst[((((size_t)b * NH + h) * T_SEQ + t) * HD + 56)] = val;
        }
    }
}

// Kernel 4: out(f32) = ao @ Wproj^T.
__global__ __launch_bounds__(256, 4) void gemm_proj_kernel(
    const ushort* __restrict__ A, const ushort* __restrict__ Bt,
    float* __restrict__ C)
{
    GEMM_CORE(A, Bt, 1024, 16384)
    #pragma unroll
    for (int i = 0; i < 4; ++i) {
        #pragma unroll
        for (int r = 0; r < 4; ++r) {
            const int rr = row0 + wm * 64 + i * 16 + quad * 4 + r;
            #pragma unroll
            for (int j = 0; j < 4; ++j) {
                const int cc = col0 + wn * 64 + j * 16 + lq;
                C[(size_t)rr * 1024 + cc] = acc[i][j][r];
            }
        }
    }
}

// ---------------------------------------------------------------------------
// Kernel 3: MFMA attention, WAVE OWNS 32 Q-ROWS (two 16-col S^T groups).
// One ak ds_read feeds both groups' S-MFMAs; one av read feeds both PV
// groups: 40 b128 reads per wave-chunk for 2x the prior work (-44%
// LDS-read traffic per FLOP); K/V staging serves 128 q-rows per chunk.
// R3's proven 2-barrier single-buffer skeleton. Q from global. P in a
// dedicated 128x128 buffer (wave-private rows, no extra barrier).
// LDS 64KB -> 2 blocks/CU; (256,2) so ~170-VGPR live set doesn't spill.
// Balanced q-tile map: qt = y<8 ? 15-y : y-8 -> any CU pair {c,c+256}
// sums to exactly 17 chunks.
// ---------------------------------------------------------------------------
#define SOFTMAX_G(sarr, qrow, lsum, prowX) do {                               \
    _Pragma("unroll") for (int nt = 0; nt < 8; ++nt) {                        \
        f32x4 sv = (sarr)[nt];                                                \
        const int kb = k0 + nt * 16 + quad * 4;                               \
        _Pragma("unroll") for (int r = 0; r < 4; ++r)                         \
            if (kb + r > (qrow)) sv[r] = NEGINF;                              \
        const float p0 = EXP2(sv[0]), p1 = EXP2(sv[1]);                       \
        const float p2 = EXP2(sv[2]), p3 = EXP2(sv[3]);                       \
        (lsum) += (p0 + p1) + (p2 + p3);                                      \
        const int pcol = (nt * 16 + quad * 4) ^ (l7 << 3);                    \
        uint2 pv; pv.x = pack_bf16(p0, p1); pv.y = pack_bf16(p2, p3);         \
        *(uint2*)&Ps[(prowX) + pcol] = pv;                                    \
    }                                                                         \
} while (0)

__global__ __launch_bounds__(256, 2) void attn_kernel(
    const ushort* __restrict__ qa, const ushort* __restrict__ ka,
    const ushort* __restrict__ vt, const float* __restrict__ bias_pre,
    ushort* __restrict__ out)
{
    __shared__ __align__(16) ushort Ks[128 * 64];    // 16 KiB
    __shared__ __align__(16) ushort Vs[64 * 128];    // 16 KiB
    __shared__ __align__(16) ushort Ps[128 * 128];   // 32 KiB (128 q-rows)
    const int bh = blockIdx.x;
    const int yy = blockIdx.y;
    const int qt = (yy < 8) ? (15 - yy) : (yy - 8);   // balanced heavy/light
    const int h = bh & 15, b = bh >> 4;
    const int tid = threadIdx.x;
    const int wave = tid >> 6, lane = tid & 63;
    const int quad = lane >> 4, lq = lane & 15;
    const int l7 = lq & 7;
    const size_t base = (size_t)bh * T_SEQ * HD;

    const int row_base = qt * 128 + wave * 32;
    const int qrow0 = row_base + lq;         // group 0
    const int qrow1 = row_base + 16 + lq;    // group 1
    const int prow0 = (wave * 32 + lq) * 128;
    const int prow1 = prow0 + 16 * 128;
    const int nc = qt + 1;
    const float* bias_h = &bias_pre[h * T_SEQ];

    // Q fragments straight from global (one-time, L2-hot, 16B/lane)
    short8 bq0[2], bq1[2];
    #pragma unroll
    for (int ks = 0; ks < 2; ++ks) {
        const int dq = (ks * 4 + quad) * 8;
        bq0[ks] = *(const short8*)&qa[base + (size_t)qrow0 * 64 + dq];
        bq1[ks] = *(const short8*)&qa[base + (size_t)qrow1 * 64 + dq];
    }

    f32x4 o40[4], o41[4];
    #pragma unroll
    for (int dt = 0; dt < 4; ++dt) {
        o40[dt] = (f32x4){0.f, 0.f, 0.f, 0.f};
        o41[dt] = (f32x4){0.f, 0.f, 0.f, 0.f};
    }
    float lsum0 = 0.f, lsum1 = 0.f;

    for (int c = 0; c < nc; ++c) {
        const int k0 = c * 128;
        if (c) __syncthreads();   // prev chunk's LDS reads done before restage
        #pragma unroll
        for (int rep = 0; rep < 4; ++rep) {
            const int idx = rep * 256 + tid;
            const int row = idx >> 3, slot = idx & 7;
            gl2lds16(&ka[base + (size_t)(k0 + row) * 64 + ((slot ^ (row & 7)) << 3)],
                     &Ks[idx * 8]);
        }
        #pragma unroll
        for (int rep = 0; rep < 4; ++rep) {
            const int idx = rep * 256 + tid;
            const int row = idx >> 4, slot = idx & 15;
            gl2lds16(&vt[base + (size_t)row * T_SEQ + k0 + ((slot ^ (row & 15)) << 3)],
                     &Vs[idx * 8]);
        }
        __syncthreads();

        // S for both groups: one ak read feeds two MFMAs
        f32x4 s0[8], s1[8];
        #pragma unroll
        for (int nt = 0; nt < 8; ++nt) {
            const f32x4 bv = *(const f32x4*)&bias_h[k0 + nt * 16 + quad * 4];
            s0[nt] = bv; s1[nt] = bv;
        }
        __builtin_amdgcn_s_setprio(1);
        #pragma unroll
        for (int ks = 0; ks < 2; ++ks)
            #pragma unroll
            for (int nt = 0; nt < 8; ++nt) {
                const short8 ak = *(const short8*)
                    &Ks[(nt * 16 + lq) * 64 + (((ks * 4 + quad) ^ l7) << 3)];
                s0[nt] = __builtin_amdgcn_mfma_f32_16x16x32_bf16(
                    ak, bq0[ks], s0[nt], 0, 0, 0);
                s1[nt] = __builtin_amdgcn_mfma_f32_16x16x32_bf16(
                    ak, bq1[ks], s1[nt], 0, 0, 0);
            }
        __builtin_amdgcn_s_setprio(0);

        SOFTMAX_G(s0, qrow0, lsum0, prow0);
        SOFTMAX_G(s1, qrow1, lsum1, prow1);
        // P rows are wave-private: same-wave DS ordering suffices, no barrier

        __builtin_amdgcn_s_setprio(1);
        #pragma unroll
        for (int ks = 0; ks < 4; ++ks) {
            const int pofc = (ks * 32 + quad * 8) ^ (l7 << 3);
            const short8 bp0 = *(const short8*)&Ps[prow0 + pofc];
            const short8 bp1 = *(const short8*)&Ps[prow1 + pofc];
            #pragma unroll
            for (int dt = 0; dt < 4; ++dt) {
                const short8 av = *(const short8*)
                    &Vs[(dt * 16 + lq) * 128 + (((ks * 4 + quad) ^ lq) << 3)];
                o40[dt] = __builtin_amdgcn_mfma_f32_16x16x32_bf16(
                    av, bp0, o40[dt], 0, 0, 0);
                o41[dt] = __builtin_amdgcn_mfma_f32_16x16x32_bf16(
                    av, bp1, o41[dt], 0, 0, 0);
            }
        }
        __builtin_amdgcn_s_setprio(0);
    }

    // row sums: lanes {lq, lq+16, lq+32, lq+48} hold disjoint key subsets
    lsum0 += __shfl_xor(lsum0, 16, 64);
    lsum0 += __shfl_xor(lsum0, 32, 64);
    lsum1 += __shfl_xor(lsum1, 16, 64);
    lsum1 += __shfl_xor(lsum1, 32, 64);
    const float inv0 = 1.0f / lsum0, inv1 = 1.0f / lsum1;
    const size_t ob0 = ((size_t)b * T_SEQ + qrow0) * CEMB + h * HD;
    const size_t ob1 = ((size_t)b * T_SEQ + qrow1) * CEMB + h * HD;
    #pragma unroll
    for (int dt = 0; dt < 4; ++dt) {
        ushort4 ov;
        ov.x = f2b_fast(o40[dt][0] * inv0);
        ov.y = f2b_fast(o40[dt][1] * inv0);
        ov.z = f2b_fast(o40[dt][2] * inv0);
        ov.w = f2b_fast(o40[dt][3] * inv0);
        *(ushort4*)&out[ob0 + dt * 16 + quad * 4] = ov;
        ushort4 ow;
        ow.x = f2b_fast(o41[dt][0] * inv1);
        ow.y = f2b_fast(o41[dt][1] * inv1);
        ow.z = f2b_fast(o41[dt][2] * inv1);
        ow.w = f2b_fast(o41[dt][3] * inv1);
        *(ushort4*)&out[ob1 + dt * 16 + quad * 4] = ow;
    }
}

// ---------------------------------------------------------------------------
extern "C" void kernel_launch(void* const* d_in, const int* in_sizes, int n_in,
                              void* d_out, int out_size, void* d_ws, size_t ws_size,
                              hipStream_t stream) {
    const float* x       = (const float*)d_in[0];
    const float* Wqkv    = (const float*)d_in[1];
    const float* Wproj   = (const float*)d_in[2];
    const float* W_recip = (const float*)d_in[3];
    const float* w_std   = (const float*)d_in[4];
    const float* w_rec   = (const float*)d_in[5];
    const float* w_disc  = (const float*)d_in[6];
    const float* d_bias  = (const float*)d_in[7];
    float* out = (float*)d_out;

    const size_t NX = (size_t)4096 * 1024;
    const size_t NWQKVX = (size_t)3328 * 1024;
    const size_t NWPROJ = (size_t)1024 * 1024;
    ushort* xb     = (ushort*)d_ws;
    ushort* wqkvb  = xb + NX;
    ushort* wprojb = wqkvb + NWQKVX;
    ushort* qh     = wprojb + NWPROJ;
    ushort* kh     = qh + NX;
    ushort* vt     = kh + NX;
    ushort* ao     = vt + NX;
    float*  bias_pre = (float*)(ao + NX);   // 16*2048 f32 = 128 KiB

    prep_kernel<<<8240, 256, 0, stream>>>(x, Wqkv, Wproj, W_recip, w_disc, d_bias,
                                          xb, wqkvb, wprojb, bias_pre);
    gemm_qkv_kernel<<<dim3(32, 26), 256, 0, stream>>>(xb, wqkvb, w_std, w_rec, qh, kh, vt);
    attn_kernel<<<dim3(32, 16), 256, 0, stream>>>(qh, kh, vt, bias_pre, ao);
    gemm_proj_kernel<<<dim3(32, 8), 256, 0, stream>>>(ao, wprojb, out);
}

// Round 10
// 188.630 us; speedup vs baseline: 1.0608x; 1.0608x over previous
//
#include <hip/hip_runtime.h>
#include <math.h>

#define T_SEQ 2048
#define NH 16
#define HD 64
#define CEMB 1024
#define NEGINF -3.0e38f
#define LOG2E 1.4426950408889634f

typedef unsigned short ushort;
typedef unsigned int uint;
typedef __attribute__((ext_vector_type(8))) short short8;
typedef __attribute__((ext_vector_type(4))) float f32x4;

#if __has_builtin(__builtin_amdgcn_exp2f)
#define EXP2(x) __builtin_amdgcn_exp2f(x)
#else
#define EXP2(x) exp2f(x)
#endif

__device__ __forceinline__ float b2f(ushort h) {
    union { uint u; float f; } cv; cv.u = ((uint)h) << 16; return cv.f;
}
__device__ __forceinline__ ushort f2b(float f) {
    union { float f; uint u; } cv; cv.f = f;
    return (ushort)((cv.u + 0x7FFF + ((cv.u >> 16) & 1)) >> 16);
}
__device__ __forceinline__ ushort f2b_fast(float f) {   // round-half-up, 2 ops
    union { float f; uint u; } cv; cv.f = f;
    return (ushort)((cv.u + 0x8000) >> 16);
}
// pack two f32 -> packed bf16 pair (round-half-up) with one v_perm_b32
__device__ __forceinline__ uint pack_bf16(float a, float b) {
    union { float f; uint u; } ua, ub; ua.f = a; ub.f = b;
    return __builtin_amdgcn_perm(ub.u + 0x8000u, ua.u + 0x8000u, 0x07060302u);
}
__device__ __forceinline__ void gl2lds16(const ushort* g, ushort* l) {
    __builtin_amdgcn_global_load_lds(
        (const __attribute__((address_space(1))) void*)g,
        (__attribute__((address_space(3))) void*)l, 16, 0, 0);
}

// ---------------------------------------------------------------------------
// prep: merged f32->bf16 convert for x/Wqkv/Wproj + Wlow rows + bias_pre.
// ---------------------------------------------------------------------------
__global__ __launch_bounds__(256) void prep_kernel(
    const float* __restrict__ x, const float* __restrict__ Wqkv,
    const float* __restrict__ Wproj, const float* __restrict__ W_recip,
    const float* __restrict__ w_disc, const float* __restrict__ d_bias,
    ushort* __restrict__ xb, ushort* __restrict__ wqkvb,
    ushort* __restrict__ wprojb, float* __restrict__ bias_pre)
{
    const int bid = blockIdx.x;
    if (bid < 8192) {
        const float* src; ushort* dst; int off;
        if (bid < 4096)      { src = x;     dst = xb;     off = bid; }
        else if (bid < 7168) { src = Wqkv;  dst = wqkvb;  off = bid - 4096; }
        else                 { src = Wproj; dst = wprojb; off = bid - 7168; }
        const int i = (off * 256 + threadIdx.x) * 4;
        const float4 v = *(const float4*)&src[i];
        ushort4 o;
        o.x = f2b(v.x); o.y = f2b(v.y); o.z = f2b(v.z); o.w = f2b(v.w);
        *(ushort4*)&dst[i] = o;
        return;
    }
    if (bid >= 8224) {
        const int h = bid - 8224;
        const float wd = w_disc[h] * LOG2E;
        const int j = h * T_SEQ + threadIdx.x * 8;
        const float4 a = *(const float4*)&d_bias[j];
        const float4 c = *(const float4*)&d_bias[j + 4];
        float4 oa, oc;
        oa.x = a.x * wd; oa.y = a.y * wd; oa.z = a.z * wd; oa.w = a.w * wd;
        oc.x = c.x * wd; oc.y = c.y * wd; oc.z = c.z * wd; oc.w = c.w * wd;
        *(float4*)&bias_pre[j] = oa;
        *(float4*)&bias_pre[j + 4] = oc;
        return;
    }
    const int wb = bid - 8192;
    const int qk = wb >> 4, h = wb & 15;
    const int e0 = threadIdx.x * 4;
    f32x4 acc[8];
    #pragma unroll
    for (int r = 0; r < 8; ++r) acc[r] = (f32x4){0.f, 0.f, 0.f, 0.f};
    #pragma unroll 4
    for (int d = 0; d < 64; ++d) {
        const float4 xv = *(const float4*)&Wqkv[(size_t)(qk * 1024 + h * 64 + d) * 1024 + e0];
        #pragma unroll
        for (int r = 0; r < 8; ++r) {
            const float w = W_recip[d * 8 + r];
            acc[r][0] = fmaf(w, xv.x, acc[r][0]);
            acc[r][1] = fmaf(w, xv.y, acc[r][1]);
            acc[r][2] = fmaf(w, xv.z, acc[r][2]);
            acc[r][3] = fmaf(w, xv.w, acc[r][3]);
        }
    }
    #pragma unroll
    for (int r = 0; r < 8; ++r) {
        ushort4 o;
        o.x = f2b(acc[r][0]); o.y = f2b(acc[r][1]);
        o.z = f2b(acc[r][2]); o.w = f2b(acc[r][3]);
        *(ushort4*)&wqkvb[(size_t)(3072 + qk * 128 + h * 8 + r) * 1024 + e0] = o;
    }
}

// ---------------------------------------------------------------------------
// bf16 MFMA GEMM core (128x128 tile, BK=64, 4 waves, global_load_lds staging,
// XOR-swizzled LDS both sides).
// ---------------------------------------------------------------------------
#define GEMM_CORE(Aptr, Bptr, KDIM, SMEMN)                                     \
    __shared__ __align__(16) ushort SMEM[SMEMN];                               \
    ushort* const Asl = SMEM;                                                  \
    ushort* const Bsl = SMEM + 8192;                                           \
    const int row0 = blockIdx.x * 128;                                         \
    const int col0 = blockIdx.y * 128;                                         \
    const int tid = threadIdx.x;                                               \
    const int wave = tid >> 6, lane = tid & 63;                                \
    const int wm = wave >> 1, wn = wave & 1;                                   \
    const int quad = lane >> 4, lq = lane & 15;                                \
    const int l7 = lq & 7;                                                     \
    f32x4 acc[4][4];                                                           \
    _Pragma("unroll") for (int i = 0; i < 4; ++i)                              \
        _Pragma("unroll") for (int j = 0; j < 4; ++j)                          \
            acc[i][j] = (f32x4){0.f, 0.f, 0.f, 0.f};                           \
    for (int k0 = 0; k0 < (KDIM); k0 += 64) {                                  \
        _Pragma("unroll") for (int p = 0; p < 4; ++p) {                        \
            const int idx = p * 256 + tid;                                     \
            const int row = idx >> 3, slot = idx & 7;                          \
            const int kc = (slot ^ (row & 7)) << 3;                            \
            gl2lds16(&(Aptr)[(size_t)(row0 + row) * (KDIM) + k0 + kc], &Asl[idx * 8]); \
            gl2lds16(&(Bptr)[(size_t)(col0 + row) * (KDIM) + k0 + kc], &Bsl[idx * 8]); \
        }                                                                      \
        __syncthreads();                                                       \
        _Pragma("unroll") for (int ks = 0; ks < 2; ++ks) {                     \
            short8 af[4], bf[4];                                               \
            _Pragma("unroll") for (int i = 0; i < 4; ++i)                      \
                af[i] = *(const short8*)&Asl[(wm * 64 + i * 16 + lq) * 64 +    \
                                             (((ks * 4 + quad) ^ l7) << 3)];   \
            _Pragma("unroll") for (int j = 0; j < 4; ++j)                      \
                bf[j] = *(const short8*)&Bsl[(wn * 64 + j * 16 + lq) * 64 +    \
                                             (((ks * 4 + quad) ^ l7) << 3)];   \
            _Pragma("unroll") for (int i = 0; i < 4; ++i)                      \
                _Pragma("unroll") for (int j = 0; j < 4; ++j)                  \
                    acc[i][j] = __builtin_amdgcn_mfma_f32_16x16x32_bf16(       \
                        af[i], bf[j], acc[i][j], 0, 0, 0);                     \
        }                                                                      \
        __syncthreads();                                                       \
    }

// Kernel 1: extended qkv GEMM, N=3328. Epilogue Cs stride = 144 ushort
// (row-to-row bank step 8 -> the 4 quad-rows of each store hit disjoint
// 8-bank groups; kills the epilogue bank conflicts).
#define CSTR 144
__global__ __launch_bounds__(256, 4) void gemm_qkv_kernel(
    const ushort* __restrict__ A, const ushort* __restrict__ Bt,
    const float* __restrict__ w_std, const float* __restrict__ w_rec,
    ushort* __restrict__ qh, ushort* __restrict__ kh, ushort* __restrict__ vt)
{
    GEMM_CORE(A, Bt, 1024, 128 * CSTR)
    ushort* const Cs = SMEM;   // epilogue staging, overlays Asl/Bsl (safe)

    if (col0 >= 2048 && col0 < 3072) {
        #pragma unroll
        for (int j = 0; j < 4; ++j) {
            const int cc = col0 + wn * 64 + j * 16 + lq;
            const int h = (cc >> 6) & 15;
            const int d = cc & 63;
            #pragma unroll
            for (int i = 0; i < 4; ++i) {
                const int rr0 = row0 + wm * 64 + i * 16 + quad * 4;
                const int b = rr0 >> 11, t0 = rr0 & 2047;
                ushort4 pv;
                pv.x = f2b(acc[i][j][0]); pv.y = f2b(acc[i][j][1]);
                pv.z = f2b(acc[i][j][2]); pv.w = f2b(acc[i][j][3]);
                *(ushort4*)&vt[((((size_t)b * NH + h) * HD + d) * T_SEQ + t0)] = pv;
            }
        }
    } else if (col0 < 2048) {
        const bool isq = (col0 < 1024);
        #pragma unroll
        for (int j = 0; j < 4; ++j) {
            const int colc = wn * 64 + j * 16 + lq;
            const int h = ((col0 + colc) >> 6) & 15;
            const float sc = isq ? w_std[h] * (0.125f * LOG2E) : 1.0f;
            #pragma unroll
            for (int i = 0; i < 4; ++i)
                #pragma unroll
                for (int r = 0; r < 4; ++r)
                    Cs[(wm * 64 + i * 16 + quad * 4 + r) * CSTR + colc] =
                        f2b(acc[i][j][r] * sc);
        }
        __syncthreads();
        ushort* dst = isq ? qh : kh;
        const int hbase = (col0 >> 6) & 15;
        #pragma unroll
        for (int rep = 0; rep < 8; ++rep) {
            const int id = rep * 256 + tid;
            const int row = id >> 4, chunk = id & 15;
            if ((chunk & 7) == 7) continue;   // d=56..63 owned by tail blocks
            const int h = hbase + (chunk >> 3);
            const int d = (chunk & 7) * 8;
            const int rr = row0 + row;
            const int b = rr >> 11, t = rr & 2047;
            const uint4 val = *(const uint4*)&Cs[row * CSTR + chunk * 8];
            *(uint4*)&dst[((((size_t)b * NH + h) * T_SEQ + t) * HD + d)] = val;
        }
    } else {
        const bool isqlow = (col0 < 3200);
        #pragma unroll
        for (int j = 0; j < 4; ++j) {
            const int colc = wn * 64 + j * 16 + lq;
            const int h = colc >> 3;
            const float sc = isqlow ? 1.0f : w_rec[h] * (0.125f * LOG2E);
            #pragma unroll
            for (int i = 0; i < 4; ++i)
                #pragma unroll
                for (int r = 0; r < 4; ++r)
                    Cs[(wm * 64 + i * 16 + quad * 4 + r) * CSTR + colc] =
                        f2b(acc[i][j][r] * sc);
        }
        __syncthreads();
        ushort* dst = isqlow ? kh : qh;
        #pragma unroll
        for (int rep = 0; rep < 8; ++rep) {
            const int id = rep * 256 + tid;
            const int row = id >> 4, h = id & 15;
            const int rr = row0 + row;
            const int b = rr >> 11, t = rr & 2047;
            const uint4 val = *(const uint4*)&Cs[row * CSTR + h * 8];
            *(uint4*)&dst[((((size_t)b * NH + h) * T_SEQ + t) * HD + 56)] = val;
        }
    }
}

// Kernel 4: out(f32) = ao @ Wproj^T.
__global__ __launch_bounds__(256, 4) void gemm_proj_kernel(
    const ushort* __restrict__ A, const ushort* __restrict__ Bt,
    float* __restrict__ C)
{
    GEMM_CORE(A, Bt, 1024, 16384)
    #pragma unroll
    for (int i = 0; i < 4; ++i) {
        #pragma unroll
        for (int r = 0; r < 4; ++r) {
            const int rr = row0 + wm * 64 + i * 16 + quad * 4 + r;
            #pragma unroll
            for (int j = 0; j < 4; ++j) {
                const int cc = col0 + wn * 64 + j * 16 + lq;
                C[(size_t)rr * 1024 + cc] = acc[i][j][r];
            }
        }
    }
}

// ---------------------------------------------------------------------------
// Kernel 3: MFMA attention — EXACT R3 structure (benched 43.2us, best of 8
// variants) + T5 setprio around the MFMA clusters (only benched-positive,
// correctness-neutral delta). Paired causal q-tiles (qtA=y light, qtB=31-y
// heavy): uniform 17 tile-computes/block, 512 blocks. Per staged chunk the
// tiles run SEQUENTIALLY sharing the Ps buffer (wave-private rows, same-wave
// LDS ordering -> no extra barrier); 2 barriers/chunk. Q staged once in LDS.
// LDS 64KB -> 2 blocks/CU; (256,2) -> natural VGPR alloc, no spill.
// ---------------------------------------------------------------------------
#define TILE_COMPUTE(bq, o4, lsum, qrow, NTL) do {                            \
    f32x4 s4[8];                                                              \
    _Pragma("unroll") for (int nt = 0; nt < (NTL); ++nt)                      \
        s4[nt] = *(const f32x4*)&bias_h[k0 + nt * 16 + quad * 4];             \
    __builtin_amdgcn_s_setprio(1);                                            \
    _Pragma("unroll") for (int ks = 0; ks < 2; ++ks)                          \
        _Pragma("unroll") for (int nt = 0; nt < (NTL); ++nt) {                \
            const short8 ak = *(const short8*)                                \
                &Ks[(nt * 16 + lq) * 64 + (((ks * 4 + quad) ^ l7) << 3)];     \
            s4[nt] = __builtin_amdgcn_mfma_f32_16x16x32_bf16(                 \
                ak, (bq)[ks], s4[nt], 0, 0, 0);                               \
        }                                                                     \
    __builtin_amdgcn_s_setprio(0);                                            \
    _Pragma("unroll") for (int nt = 0; nt < (NTL); ++nt) {                    \
        f32x4 sv = s4[nt];                                                    \
        const int kb = k0 + nt * 16 + quad * 4;                               \
        _Pragma("unroll") for (int r = 0; r < 4; ++r)                         \
            if (kb + r > (qrow)) sv[r] = NEGINF;                              \
        const float p0 = EXP2(sv[0]), p1 = EXP2(sv[1]);                       \
        const float p2 = EXP2(sv[2]), p3 = EXP2(sv[3]);                       \
        (lsum) += (p0 + p1) + (p2 + p3);                                      \
        const int pcol = (nt * 16 + quad * 4) ^ (l7 << 3);                    \
        uint2 pv; pv.x = pack_bf16(p0, p1); pv.y = pack_bf16(p2, p3);         \
        *(uint2*)&Ps[prow + pcol] = pv;                                       \
    }                                                                         \
    __builtin_amdgcn_s_setprio(1);                                            \
    _Pragma("unroll") for (int ks = 0; ks < (NTL) / 2; ++ks) {                \
        const short8 bp = *(const short8*)                                    \
            &Ps[prow + ((ks * 32 + quad * 8) ^ (l7 << 3))];                   \
        _Pragma("unroll") for (int dt = 0; dt < 4; ++dt) {                    \
            const short8 bv = *(const short8*)                                \
                &Vs[(dt * 16 + lq) * 128 + (((ks * 4 + quad) ^ lq) << 3)];    \
            (o4)[dt] = __builtin_amdgcn_mfma_f32_16x16x32_bf16(               \
                bv, bp, (o4)[dt], 0, 0, 0);                                   \
        }                                                                     \
    }                                                                         \
    __builtin_amdgcn_s_setprio(0);                                            \
} while (0)

__global__ __launch_bounds__(256, 2) void attn_kernel(
    const ushort* __restrict__ qa, const ushort* __restrict__ ka,
    const ushort* __restrict__ vt, const float* __restrict__ bias_pre,
    ushort* __restrict__ out)
{
    __shared__ __align__(16) ushort Qs[2 * 64 * 64];   // 16 KiB (tiles A,B)
    __shared__ __align__(16) ushort Ks[128 * 64];      // 16 KiB
    __shared__ __align__(16) ushort Ps[64 * 128];      // 16 KiB (shared seq.)
    __shared__ __align__(16) ushort Vs[64 * 128];      // 16 KiB
    const int bh = blockIdx.x;
    const int qtA = blockIdx.y;        // light tile (0..15)
    const int qtB = 31 - blockIdx.y;   // heavy tile (16..31)
    const int h = bh & 15, b = bh >> 4;
    const int tid = threadIdx.x;
    const int wave = tid >> 6, lane = tid & 63;
    const int quad = lane >> 4, lq = lane & 15;
    const int l7 = lq & 7;
    const size_t base = (size_t)bh * T_SEQ * HD;

    // Q stage for both tiles (once), swizzled source -> linear LDS
    #pragma unroll
    for (int rep = 0; rep < 2; ++rep) {
        const int idx = rep * 256 + tid;
        const int row = idx >> 3, slot = idx & 7;
        const int kc = (slot ^ (row & 7)) << 3;
        gl2lds16(&qa[base + (size_t)(qtA * 64 + row) * 64 + kc], &Qs[idx * 8]);
        gl2lds16(&qa[base + (size_t)(qtB * 64 + row) * 64 + kc], &Qs[4096 + idx * 8]);
    }
    __syncthreads();
    short8 bqA[2], bqB[2];
    #pragma unroll
    for (int ks = 0; ks < 2; ++ks) {
        const int off = (wave * 16 + lq) * 64 + (((ks * 4 + quad) ^ l7) << 3);
        bqA[ks] = *(const short8*)&Qs[off];
        bqB[ks] = *(const short8*)&Qs[4096 + off];
    }

    f32x4 o4A[4], o4B[4];
    #pragma unroll
    for (int dt = 0; dt < 4; ++dt) {
        o4A[dt] = (f32x4){0.f, 0.f, 0.f, 0.f};
        o4B[dt] = (f32x4){0.f, 0.f, 0.f, 0.f};
    }
    float lsumA = 0.f, lsumB = 0.f;
    const int qrowA = qtA * 64 + wave * 16 + lq;
    const int qrowB = qtB * 64 + wave * 16 + lq;
    const int prow = (wave * 16 + lq) * 128;
    const int nA = (qtA + 2) >> 1, nB = (qtB + 2) >> 1;
    const float* bias_h = &bias_pre[h * T_SEQ];

    for (int c = 0; c < nB; ++c) {
        const int k0 = c * 128;
        if (c) __syncthreads();   // prev chunk's K/V/P reads done before restage
        #pragma unroll
        for (int rep = 0; rep < 4; ++rep) {
            const int idx = rep * 256 + tid;
            const int row = idx >> 3, slot = idx & 7;
            gl2lds16(&ka[base + (size_t)(k0 + row) * 64 + ((slot ^ (row & 7)) << 3)],
                     &Ks[idx * 8]);
        }
        #pragma unroll
        for (int rep = 0; rep < 4; ++rep) {
            const int idx = rep * 256 + tid;
            const int row = idx >> 4, slot = idx & 15;
            gl2lds16(&vt[base + (size_t)row * T_SEQ + k0 + ((slot ^ (row & 15)) << 3)],
                     &Vs[idx * 8]);
        }
        __syncthreads();

        // heavy tile (always active)
        if (c == nB - 1 && !(qtB & 1)) TILE_COMPUTE(bqB, o4B, lsumB, qrowB, 4);
        else                           TILE_COMPUTE(bqB, o4B, lsumB, qrowB, 8);
        // light tile (reuses Ps; wave-private rows, same-wave order suffices)
        if (c < nA) {
            if (c == nA - 1 && !(qtA & 1)) TILE_COMPUTE(bqA, o4A, lsumA, qrowA, 4);
            else                           TILE_COMPUTE(bqA, o4A, lsumA, qrowA, 8);
        }
    }

    // row sums: lanes {lq, lq+16, lq+32, lq+48} hold disjoint key subsets
    lsumA += __shfl_xor(lsumA, 16, 64);
    lsumA += __shfl_xor(lsumA, 32, 64);
    lsumB += __shfl_xor(lsumB, 16, 64);
    lsumB += __shfl_xor(lsumB, 32, 64);
    const float invA = 1.0f / lsumA, invB = 1.0f / lsumB;
    const size_t obaseA = ((size_t)b * T_SEQ + qrowA) * CEMB + h * HD;
    const size_t obaseB = ((size_t)b * T_SEQ + qrowB) * CEMB + h * HD;
    #pragma unroll
    for (int dt = 0; dt < 4; ++dt) {
        ushort4 ov;
        ov.x = f2b_fast(o4A[dt][0] * invA);
        ov.y = f2b_fast(o4A[dt][1] * invA);
        ov.z = f2b_fast(o4A[dt][2] * invA);
        ov.w = f2b_fast(o4A[dt][3] * invA);
        *(ushort4*)&out[obaseA + dt * 16 + quad * 4] = ov;
        ushort4 ow;
        ow.x = f2b_fast(o4B[dt][0] * invB);
        ow.y = f2b_fast(o4B[dt][1] * invB);
        ow.z = f2b_fast(o4B[dt][2] * invB);
        ow.w = f2b_fast(o4B[dt][3] * invB);
        *(ushort4*)&out[obaseB + dt * 16 + quad * 4] = ow;
    }
}

// ---------------------------------------------------------------------------
extern "C" void kernel_launch(void* const* d_in, const int* in_sizes, int n_in,
                              void* d_out, int out_size, void* d_ws, size_t ws_size,
                              hipStream_t stream) {
    const float* x       = (const float*)d_in[0];
    const float* Wqkv    = (const float*)d_in[1];
    const float* Wproj   = (const float*)d_in[2];
    const float* W_recip = (const float*)d_in[3];
    const float* w_std   = (const float*)d_in[4];
    const float* w_rec   = (const float*)d_in[5];
    const float* w_disc  = (const float*)d_in[6];
    const float* d_bias  = (const float*)d_in[7];
    float* out = (float*)d_out;

    const size_t NX = (size_t)4096 * 1024;
    const size_t NWQKVX = (size_t)3328 * 1024;
    const size_t NWPROJ = (size_t)1024 * 1024;
    ushort* xb     = (ushort*)d_ws;
    ushort* wqkvb  = xb + NX;
    ushort* wprojb = wqkvb + NWQKVX;
    ushort* qh     = wprojb + NWPROJ;
    ushort* kh     = qh + NX;
    ushort* vt     = kh + NX;
    ushort* ao     = vt + NX;
    float*  bias_pre = (float*)(ao + NX);   // 16*2048 f32 = 128 KiB

    prep_kernel<<<8240, 256, 0, stream>>>(x, Wqkv, Wproj, W_recip, w_disc, d_bias,
                                          xb, wqkvb, wprojb, bias_pre);
    gemm_qkv_kernel<<<dim3(32, 26), 256, 0, stream>>>(xb, wqkvb, w_std, w_rec, qh, kh, vt);
    attn_kernel<<<dim3(32, 16), 256, 0, stream>>>(qh, kh, vt, bias_pre, ao);
    gemm_proj_kernel<<<dim3(32, 8), 256, 0, stream>>>(ao, wprojb, out);
}

// Round 11
// 180.867 us; speedup vs baseline: 1.1064x; 1.0429x over previous
//
#include <hip/hip_runtime.h>
#include <math.h>

#define T_SEQ 2048
#define NH 16
#define HD 64
#define CEMB 1024
#define NEGINF -3.0e38f
#define LOG2E 1.4426950408889634f

typedef unsigned short ushort;
typedef unsigned int uint;
typedef __attribute__((ext_vector_type(8))) short short8;
typedef __attribute__((ext_vector_type(4))) float f32x4;

#if __has_builtin(__builtin_amdgcn_exp2f)
#define EXP2(x) __builtin_amdgcn_exp2f(x)
#else
#define EXP2(x) exp2f(x)
#endif

__device__ __forceinline__ float b2f(ushort h) {
    union { uint u; float f; } cv; cv.u = ((uint)h) << 16; return cv.f;
}
__device__ __forceinline__ ushort f2b(float f) {
    union { float f; uint u; } cv; cv.f = f;
    return (ushort)((cv.u + 0x7FFF + ((cv.u >> 16) & 1)) >> 16);
}
__device__ __forceinline__ ushort f2b_fast(float f) {   // round-half-up, 2 ops
    union { float f; uint u; } cv; cv.f = f;
    return (ushort)((cv.u + 0x8000) >> 16);
}
// pack two f32 -> packed bf16 pair (round-half-up) with one v_perm_b32
__device__ __forceinline__ uint pack_bf16(float a, float b) {
    union { float f; uint u; } ua, ub; ua.f = a; ub.f = b;
    return __builtin_amdgcn_perm(ub.u + 0x8000u, ua.u + 0x8000u, 0x07060302u);
}
__device__ __forceinline__ void gl2lds16(const ushort* g, ushort* l) {
    __builtin_amdgcn_global_load_lds(
        (const __attribute__((address_space(1))) void*)g,
        (__attribute__((address_space(3))) void*)l, 16, 0, 0);
}

// ---------------------------------------------------------------------------
// prep: Wlow rows FIRST (latency-bound, start early so they hide under the
// convert stream), then bias_pre, then bulk f32->bf16 converts.
//   blocks [0,32)      : Wlow = Wqkv[q|k block] @ W_recip -> wqkvb rows 3072+
//   blocks [32,48)     : bias_pre[h][t] = w_disc[h]*log2e*d_bias[h][t]
//   blocks [48,8240)   : bulk convert x/Wqkv/Wproj
// ---------------------------------------------------------------------------
__global__ __launch_bounds__(256) void prep_kernel(
    const float* __restrict__ x, const float* __restrict__ Wqkv,
    const float* __restrict__ Wproj, const float* __restrict__ W_recip,
    const float* __restrict__ w_disc, const float* __restrict__ d_bias,
    ushort* __restrict__ xb, ushort* __restrict__ wqkvb,
    ushort* __restrict__ wprojb, float* __restrict__ bias_pre)
{
    const int bid = blockIdx.x;
    if (bid >= 48) {
        const int off0 = bid - 48;
        const float* src; ushort* dst; int off;
        if (off0 < 4096)      { src = x;     dst = xb;     off = off0; }
        else if (off0 < 7168) { src = Wqkv;  dst = wqkvb;  off = off0 - 4096; }
        else                  { src = Wproj; dst = wprojb; off = off0 - 7168; }
        const int i = (off * 256 + threadIdx.x) * 4;
        const float4 v = *(const float4*)&src[i];
        ushort4 o;
        o.x = f2b(v.x); o.y = f2b(v.y); o.z = f2b(v.z); o.w = f2b(v.w);
        *(ushort4*)&dst[i] = o;
        return;
    }
    if (bid >= 32) {
        const int h = bid - 32;
        const float wd = w_disc[h] * LOG2E;
        const int j = h * T_SEQ + threadIdx.x * 8;
        const float4 a = *(const float4*)&d_bias[j];
        const float4 c = *(const float4*)&d_bias[j + 4];
        float4 oa, oc;
        oa.x = a.x * wd; oa.y = a.y * wd; oa.z = a.z * wd; oa.w = a.w * wd;
        oc.x = c.x * wd; oc.y = c.y * wd; oc.z = c.z * wd; oc.w = c.w * wd;
        *(float4*)&bias_pre[j] = oa;
        *(float4*)&bias_pre[j + 4] = oc;
        return;
    }
    const int qk = bid >> 4, h = bid & 15;
    const int e0 = threadIdx.x * 4;
    f32x4 acc[8];
    #pragma unroll
    for (int r = 0; r < 8; ++r) acc[r] = (f32x4){0.f, 0.f, 0.f, 0.f};
    #pragma unroll 4
    for (int d = 0; d < 64; ++d) {
        const float4 xv = *(const float4*)&Wqkv[(size_t)(qk * 1024 + h * 64 + d) * 1024 + e0];
        #pragma unroll
        for (int r = 0; r < 8; ++r) {
            const float w = W_recip[d * 8 + r];
            acc[r][0] = fmaf(w, xv.x, acc[r][0]);
            acc[r][1] = fmaf(w, xv.y, acc[r][1]);
            acc[r][2] = fmaf(w, xv.z, acc[r][2]);
            acc[r][3] = fmaf(w, xv.w, acc[r][3]);
        }
    }
    #pragma unroll
    for (int r = 0; r < 8; ++r) {
        ushort4 o;
        o.x = f2b(acc[r][0]); o.y = f2b(acc[r][1]);
        o.z = f2b(acc[r][2]); o.w = f2b(acc[r][3]);
        *(ushort4*)&wqkvb[(size_t)(3072 + qk * 128 + h * 8 + r) * 1024 + e0] = o;
    }
}

// ---------------------------------------------------------------------------
// bf16 MFMA GEMM core (128x128 tile, BK=64, 4 waves, global_load_lds staging,
// XOR-swizzled LDS both sides).
// ---------------------------------------------------------------------------
#define GEMM_CORE(Aptr, Bptr, KDIM, SMEMN)                                     \
    __shared__ __align__(16) ushort SMEM[SMEMN];                               \
    ushort* const Asl = SMEM;                                                  \
    ushort* const Bsl = SMEM + 8192;                                           \
    const int row0 = blockIdx.x * 128;                                         \
    const int col0 = blockIdx.y * 128;                                         \
    const int tid = threadIdx.x;                                               \
    const int wave = tid >> 6, lane = tid & 63;                                \
    const int wm = wave >> 1, wn = wave & 1;                                   \
    const int quad = lane >> 4, lq = lane & 15;                                \
    const int l7 = lq & 7;                                                     \
    f32x4 acc[4][4];                                                           \
    _Pragma("unroll") for (int i = 0; i < 4; ++i)                              \
        _Pragma("unroll") for (int j = 0; j < 4; ++j)                          \
            acc[i][j] = (f32x4){0.f, 0.f, 0.f, 0.f};                           \
    for (int k0 = 0; k0 < (KDIM); k0 += 64) {                                  \
        _Pragma("unroll") for (int p = 0; p < 4; ++p) {                        \
            const int idx = p * 256 + tid;                                     \
            const int row = idx >> 3, slot = idx & 7;                          \
            const int kc = (slot ^ (row & 7)) << 3;                            \
            gl2lds16(&(Aptr)[(size_t)(row0 + row) * (KDIM) + k0 + kc], &Asl[idx * 8]); \
            gl2lds16(&(Bptr)[(size_t)(col0 + row) * (KDIM) + k0 + kc], &Bsl[idx * 8]); \
        }                                                                      \
        __syncthreads();                                                       \
        _Pragma("unroll") for (int ks = 0; ks < 2; ++ks) {                     \
            short8 af[4], bf[4];                                               \
            _Pragma("unroll") for (int i = 0; i < 4; ++i)                      \
                af[i] = *(const short8*)&Asl[(wm * 64 + i * 16 + lq) * 64 +    \
                                             (((ks * 4 + quad) ^ l7) << 3)];   \
            _Pragma("unroll") for (int j = 0; j < 4; ++j)                      \
                bf[j] = *(const short8*)&Bsl[(wn * 64 + j * 16 + lq) * 64 +    \
                                             (((ks * 4 + quad) ^ l7) << 3)];   \
            _Pragma("unroll") for (int i = 0; i < 4; ++i)                      \
                _Pragma("unroll") for (int j = 0; j < 4; ++j)                  \
                    acc[i][j] = __builtin_amdgcn_mfma_f32_16x16x32_bf16(       \
                        af[i], bf[j], acc[i][j], 0, 0, 0);                     \
        }                                                                      \
        __syncthreads();                                                       \
    }

// Kernel 1: extended qkv GEMM, N=3328. Epilogue Cs stride = 144 ushort.
#define CSTR 144
__global__ __launch_bounds__(256, 4) void gemm_qkv_kernel(
    const ushort* __restrict__ A, const ushort* __restrict__ Bt,
    const float* __restrict__ w_std, const float* __restrict__ w_rec,
    ushort* __restrict__ qh, ushort* __restrict__ kh, ushort* __restrict__ vt)
{
    GEMM_CORE(A, Bt, 1024, 128 * CSTR)
    ushort* const Cs = SMEM;   // epilogue staging, overlays Asl/Bsl (safe)

    if (col0 >= 2048 && col0 < 3072) {
        #pragma unroll
        for (int j = 0; j < 4; ++j) {
            const int cc = col0 + wn * 64 + j * 16 + lq;
            const int h = (cc >> 6) & 15;
            const int d = cc & 63;
            #pragma unroll
            for (int i = 0; i < 4; ++i) {
                const int rr0 = row0 + wm * 64 + i * 16 + quad * 4;
                const int b = rr0 >> 11, t0 = rr0 & 2047;
                ushort4 pv;
                pv.x = f2b(acc[i][j][0]); pv.y = f2b(acc[i][j][1]);
                pv.z = f2b(acc[i][j][2]); pv.w = f2b(acc[i][j][3]);
                *(ushort4*)&vt[((((size_t)b * NH + h) * HD + d) * T_SEQ + t0)] = pv;
            }
        }
    } else if (col0 < 2048) {
        const bool isq = (col0 < 1024);
        #pragma unroll
        for (int j = 0; j < 4; ++j) {
            const int colc = wn * 64 + j * 16 + lq;
            const int h = ((col0 + colc) >> 6) & 15;
            const float sc = isq ? w_std[h] * (0.125f * LOG2E) : 1.0f;
            #pragma unroll
            for (int i = 0; i < 4; ++i)
                #pragma unroll
                for (int r = 0; r < 4; ++r)
                    Cs[(wm * 64 + i * 16 + quad * 4 + r) * CSTR + colc] =
                        f2b(acc[i][j][r] * sc);
        }
        __syncthreads();
        ushort* dst = isq ? qh : kh;
        const int hbase = (col0 >> 6) & 15;
        #pragma unroll
        for (int rep = 0; rep < 8; ++rep) {
            const int id = rep * 256 + tid;
            const int row = id >> 4, chunk = id & 15;
            if ((chunk & 7) == 7) continue;   // d=56..63 owned by tail blocks
            const int h = hbase + (chunk >> 3);
            const int d = (chunk & 7) * 8;
            const int rr = row0 + row;
            const int b = rr >> 11, t = rr & 2047;
            const uint4 val = *(const uint4*)&Cs[row * CSTR + chunk * 8];
            *(uint4*)&dst[((((size_t)b * NH + h) * T_SEQ + t) * HD + d)] = val;
        }
    } else {
        const bool isqlow = (col0 < 3200);
        #pragma unroll
        for (int j = 0; j < 4; ++j) {
            const int colc = wn * 64 + j * 16 + lq;
            const int h = colc >> 3;
            const float sc = isqlow ? 1.0f : w_rec[h] * (0.125f * LOG2E);
            #pragma unroll
            for (int i = 0; i < 4; ++i)
                #pragma unroll
                for (int r = 0; r < 4; ++r)
                    Cs[(wm * 64 + i * 16 + quad * 4 + r) * CSTR + colc] =
                        f2b(acc[i][j][r] * sc);
        }
        __syncthreads();
        ushort* dst = isqlow ? kh : qh;
        #pragma unroll
        for (int rep = 0; rep < 8; ++rep) {
            const int id = rep * 256 + tid;
            const int row = id >> 4, h = id & 15;
            const int rr = row0 + row;
            const int b = rr >> 11, t = rr & 2047;
            const uint4 val = *(const uint4*)&Cs[row * CSTR + h * 8];
            *(uint4*)&dst[((((size_t)b * NH + h) * T_SEQ + t) * HD + 56)] = val;
        }
    }
}

// ---------------------------------------------------------------------------
// Kernel 4: out(f32) = ao @ Wproj^T — 128x64 tiles, grid (32,16) = 512
// blocks = 2 blocks/CU (was 256 = 1/CU: zero cross-block overlap, every
// barrier drain exposed). 4 waves x 32x64 sub-tiles (acc[2][4]).
// LDS 24KB (Asl 128x64 + Bsl 64x64), same XOR swizzle as GEMM_CORE.
// ---------------------------------------------------------------------------
__global__ __launch_bounds__(256, 4) void gemm_proj_kernel(
    const ushort* __restrict__ A, const ushort* __restrict__ Bt,
    float* __restrict__ C)
{
    __shared__ __align__(16) ushort SMEM[12288];
    ushort* const Asl = SMEM;            // 128 x 64
    ushort* const Bsl = SMEM + 8192;     // 64 x 64
    const int row0 = blockIdx.x * 128;
    const int col0 = blockIdx.y * 64;
    const int tid = threadIdx.x;
    const int wave = tid >> 6, lane = tid & 63;
    const int quad = lane >> 4, lq = lane & 15;
    const int l7 = lq & 7;
    f32x4 acc[2][4];
    #pragma unroll
    for (int i = 0; i < 2; ++i)
        #pragma unroll
        for (int j = 0; j < 4; ++j)
            acc[i][j] = (f32x4){0.f, 0.f, 0.f, 0.f};

    for (int k0 = 0; k0 < 1024; k0 += 64) {
        #pragma unroll
        for (int p = 0; p < 4; ++p) {
            const int idx = p * 256 + tid;
            const int row = idx >> 3, slot = idx & 7;
            const int kc = (slot ^ (row & 7)) << 3;
            gl2lds16(&A[(size_t)(row0 + row) * 1024 + k0 + kc], &Asl[idx * 8]);
        }
        #pragma unroll
        for (int p = 0; p < 2; ++p) {
            const int idx = p * 256 + tid;
            const int row = idx >> 3, slot = idx & 7;
            const int kc = (slot ^ (row & 7)) << 3;
            gl2lds16(&Bt[(size_t)(col0 + row) * 1024 + k0 + kc], &Bsl[idx * 8]);
        }
        __syncthreads();
        #pragma unroll
        for (int ks = 0; ks < 2; ++ks) {
            short8 af[2], bf[4];
            #pragma unroll
            for (int i = 0; i < 2; ++i)
                af[i] = *(const short8*)&Asl[(wave * 32 + i * 16 + lq) * 64 +
                                             (((ks * 4 + quad) ^ l7) << 3)];
            #pragma unroll
            for (int j = 0; j < 4; ++j)
                bf[j] = *(const short8*)&Bsl[(j * 16 + lq) * 64 +
                                             (((ks * 4 + quad) ^ l7) << 3)];
            #pragma unroll
            for (int i = 0; i < 2; ++i)
                #pragma unroll
                for (int j = 0; j < 4; ++j)
                    acc[i][j] = __builtin_amdgcn_mfma_f32_16x16x32_bf16(
                        af[i], bf[j], acc[i][j], 0, 0, 0);
        }
        __syncthreads();
    }
    #pragma unroll
    for (int i = 0; i < 2; ++i) {
        #pragma unroll
        for (int r = 0; r < 4; ++r) {
            const int rr = row0 + wave * 32 + i * 16 + quad * 4 + r;
            #pragma unroll
            for (int j = 0; j < 4; ++j) {
                const int cc = col0 + j * 16 + lq;
                C[(size_t)rr * 1024 + cc] = acc[i][j][r];
            }
        }
    }
}

// ---------------------------------------------------------------------------
// Kernel 3: MFMA attention — R3 structure + setprio (benched 44.1us R10).
// Paired causal q-tiles, sequential tiles sharing Ps, 2 barriers/chunk.
// LDS 64KB -> 2 blocks/CU; (256,2) -> natural VGPR alloc, no spill.
// ---------------------------------------------------------------------------
#define TILE_COMPUTE(bq, o4, lsum, qrow, NTL) do {                            \
    f32x4 s4[8];                                                              \
    _Pragma("unroll") for (int nt = 0; nt < (NTL); ++nt)                      \
        s4[nt] = *(const f32x4*)&bias_h[k0 + nt * 16 + quad * 4];             \
    __builtin_amdgcn_s_setprio(1);                                            \
    _Pragma("unroll") for (int ks = 0; ks < 2; ++ks)                          \
        _Pragma("unroll") for (int nt = 0; nt < (NTL); ++nt) {                \
            const short8 ak = *(const short8*)                                \
                &Ks[(nt * 16 + lq) * 64 + (((ks * 4 + quad) ^ l7) << 3)];     \
            s4[nt] = __builtin_amdgcn_mfma_f32_16x16x32_bf16(                 \
                ak, (bq)[ks], s4[nt], 0, 0, 0);                               \
        }                                                                     \
    __builtin_amdgcn_s_setprio(0);                                            \
    _Pragma("unroll") for (int nt = 0; nt < (NTL); ++nt) {                    \
        f32x4 sv = s4[nt];                                                    \
        const int kb = k0 + nt * 16 + quad * 4;                               \
        _Pragma("unroll") for (int r = 0; r < 4; ++r)                         \
            if (kb + r > (qrow)) sv[r] = NEGINF;                              \
        const float p0 = EXP2(sv[0]), p1 = EXP2(sv[1]);                       \
        const float p2 = EXP2(sv[2]), p3 = EXP2(sv[3]);                       \
        (lsum) += (p0 + p1) + (p2 + p3);                                      \
        const int pcol = (nt * 16 + quad * 4) ^ (l7 << 3);                    \
        uint2 pv; pv.x = pack_bf16(p0, p1); pv.y = pack_bf16(p2, p3);         \
        *(uint2*)&Ps[prow + pcol] = pv;                                       \
    }                                                                         \
    __builtin_amdgcn_s_setprio(1);                                            \
    _Pragma("unroll") for (int ks = 0; ks < (NTL) / 2; ++ks) {                \
        const short8 bp = *(const short8*)                                    \
            &Ps[prow + ((ks * 32 + quad * 8) ^ (l7 << 3))];                   \
        _Pragma("unroll") for (int dt = 0; dt < 4; ++dt) {                    \
            const short8 bv = *(const short8*)                                \
                &Vs[(dt * 16 + lq) * 128 + (((ks * 4 + quad) ^ lq) << 3)];    \
            (o4)[dt] = __builtin_amdgcn_mfma_f32_16x16x32_bf16(               \
                bv, bp, (o4)[dt], 0, 0, 0);                                   \
        }                                                                     \
    }                                                                         \
    __builtin_amdgcn_s_setprio(0);                                            \
} while (0)

__global__ __launch_bounds__(256, 2) void attn_kernel(
    const ushort* __restrict__ qa, const ushort* __restrict__ ka,
    const ushort* __restrict__ vt, const float* __restrict__ bias_pre,
    ushort* __restrict__ out)
{
    __shared__ __align__(16) ushort Qs[2 * 64 * 64];   // 16 KiB (tiles A,B)
    __shared__ __align__(16) ushort Ks[128 * 64];      // 16 KiB
    __shared__ __align__(16) ushort Ps[64 * 128];      // 16 KiB (shared seq.)
    __shared__ __align__(16) ushort Vs[64 * 128];      // 16 KiB
    const int bh = blockIdx.x;
    const int qtA = blockIdx.y;        // light tile (0..15)
    const int qtB = 31 - blockIdx.y;   // heavy tile (16..31)
    const int h = bh & 15, b = bh >> 4;
    const int tid = threadIdx.x;
    const int wave = tid >> 6, lane = tid & 63;
    const int quad = lane >> 4, lq = lane & 15;
    const int l7 = lq & 7;
    const size_t base = (size_t)bh * T_SEQ * HD;

    // Q stage for both tiles (once), swizzled source -> linear LDS
    #pragma unroll
    for (int rep = 0; rep < 2; ++rep) {
        const int idx = rep * 256 + tid;
        const int row = idx >> 3, slot = idx & 7;
        const int kc = (slot ^ (row & 7)) << 3;
        gl2lds16(&qa[base + (size_t)(qtA * 64 + row) * 64 + kc], &Qs[idx * 8]);
        gl2lds16(&qa[base + (size_t)(qtB * 64 + row) * 64 + kc], &Qs[4096 + idx * 8]);
    }
    __syncthreads();
    short8 bqA[2], bqB[2];
    #pragma unroll
    for (int ks = 0; ks < 2; ++ks) {
        const int off = (wave * 16 + lq) * 64 + (((ks * 4 + quad) ^ l7) << 3);
        bqA[ks] = *(const short8*)&Qs[off];
        bqB[ks] = *(const short8*)&Qs[4096 + off];
    }

    f32x4 o4A[4], o4B[4];
    #pragma unroll
    for (int dt = 0; dt < 4; ++dt) {
        o4A[dt] = (f32x4){0.f, 0.f, 0.f, 0.f};
        o4B[dt] = (f32x4){0.f, 0.f, 0.f, 0.f};
    }
    float lsumA = 0.f, lsumB = 0.f;
    const int qrowA = qtA * 64 + wave * 16 + lq;
    const int qrowB = qtB * 64 + wave * 16 + lq;
    const int prow = (wave * 16 + lq) * 128;
    const int nA = (qtA + 2) >> 1, nB = (qtB + 2) >> 1;
    const float* bias_h = &bias_pre[h * T_SEQ];

    for (int c = 0; c < nB; ++c) {
        const int k0 = c * 128;
        if (c) __syncthreads();   // prev chunk's K/V/P reads done before restage
        #pragma unroll
        for (int rep = 0; rep < 4; ++rep) {
            const int idx = rep * 256 + tid;
            const int row = idx >> 3, slot = idx & 7;
            gl2lds16(&ka[base + (size_t)(k0 + row) * 64 + ((slot ^ (row & 7)) << 3)],
                     &Ks[idx * 8]);
        }
        #pragma unroll
        for (int rep = 0; rep < 4; ++rep) {
            const int idx = rep * 256 + tid;
            const int row = idx >> 4, slot = idx & 15;
            gl2lds16(&vt[base + (size_t)row * T_SEQ + k0 + ((slot ^ (row & 15)) << 3)],
                     &Vs[idx * 8]);
        }
        __syncthreads();

        // heavy tile (always active)
        if (c == nB - 1 && !(qtB & 1)) TILE_COMPUTE(bqB, o4B, lsumB, qrowB, 4);
        else                           TILE_COMPUTE(bqB, o4B, lsumB, qrowB, 8);
        // light tile (reuses Ps; wave-private rows, same-wave order suffices)
        if (c < nA) {
            if (c == nA - 1 && !(qtA & 1)) TILE_COMPUTE(bqA, o4A, lsumA, qrowA, 4);
            else                           TILE_COMPUTE(bqA, o4A, lsumA, qrowA, 8);
        }
    }

    // row sums: lanes {lq, lq+16, lq+32, lq+48} hold disjoint key subsets
    lsumA += __shfl_xor(lsumA, 16, 64);
    lsumA += __shfl_xor(lsumA, 32, 64);
    lsumB += __shfl_xor(lsumB, 16, 64);
    lsumB += __shfl_xor(lsumB, 32, 64);
    const float invA = 1.0f / lsumA, invB = 1.0f / lsumB;
    const size_t obaseA = ((size_t)b * T_SEQ + qrowA) * CEMB + h * HD;
    const size_t obaseB = ((size_t)b * T_SEQ + qrowB) * CEMB + h * HD;
    #pragma unroll
    for (int dt = 0; dt < 4; ++dt) {
        ushort4 ov;
        ov.x = f2b_fast(o4A[dt][0] * invA);
        ov.y = f2b_fast(o4A[dt][1] * invA);
        ov.z = f2b_fast(o4A[dt][2] * invA);
        ov.w = f2b_fast(o4A[dt][3] * invA);
        *(ushort4*)&out[obaseA + dt * 16 + quad * 4] = ov;
        ushort4 ow;
        ow.x = f2b_fast(o4B[dt][0] * invB);
        ow.y = f2b_fast(o4B[dt][1] * invB);
        ow.z = f2b_fast(o4B[dt][2] * invB);
        ow.w = f2b_fast(o4B[dt][3] * invB);
        *(ushort4*)&out[obaseB + dt * 16 + quad * 4] = ow;
    }
}

// ---------------------------------------------------------------------------
extern "C" void kernel_launch(void* const* d_in, const int* in_sizes, int n_in,
                              void* d_out, int out_size, void* d_ws, size_t ws_size,
                              hipStream_t stream) {
    const float* x       = (const float*)d_in[0];
    const float* Wqkv    = (const float*)d_in[1];
    const float* Wproj   = (const float*)d_in[2];
    const float* W_recip = (const float*)d_in[3];
    const float* w_std   = (const float*)d_in[4];
    const float* w_rec   = (const float*)d_in[5];
    const float* w_disc  = (const float*)d_in[6];
    const float* d_bias  = (const float*)d_in[7];
    float* out = (float*)d_out;

    const size_t NX = (size_t)4096 * 1024;
    const size_t NWQKVX = (size_t)3328 * 1024;
    const size_t NWPROJ = (size_t)1024 * 1024;
    ushort* xb     = (ushort*)d_ws;
    ushort* wqkvb  = xb + NX;
    ushort* wprojb = wqkvb + NWQKVX;
    ushort* qh     = wprojb + NWPROJ;
    ushort* kh     = qh + NX;
    ushort* vt     = kh + NX;
    ushort* ao     = vt + NX;
    float*  bias_pre = (float*)(ao + NX);   // 16*2048 f32 = 128 KiB

    prep_kernel<<<8240, 256, 0, stream>>>(x, Wqkv, Wproj, W_recip, w_disc, d_bias,
                                          xb, wqkvb, wprojb, bias_pre);
    gemm_qkv_kernel<<<dim3(32, 26), 256, 0, stream>>>(xb, wqkvb, w_std, w_rec, qh, kh, vt);
    attn_kernel<<<dim3(32, 16), 256, 0, stream>>>(qh, kh, vt, bias_pre, ao);
    gemm_proj_kernel<<<dim3(32, 16), 256, 0, stream>>>(ao, wprojb, out);
}

// Round 12
// 175.177 us; speedup vs baseline: 1.1423x; 1.0325x over previous
//
#include <hip/hip_runtime.h>
#include <math.h>

#define T_SEQ 2048
#define NH 16
#define HD 64
#define CEMB 1024
#define NEGINF -3.0e38f
#define LOG2E 1.4426950408889634f

typedef unsigned short ushort;
typedef unsigned int uint;
typedef __attribute__((ext_vector_type(8))) short short8;
typedef __attribute__((ext_vector_type(4))) float f32x4;

#if __has_builtin(__builtin_amdgcn_exp2f)
#define EXP2(x) __builtin_amdgcn_exp2f(x)
#else
#define EXP2(x) exp2f(x)
#endif

__device__ __forceinline__ float b2f(ushort h) {
    union { uint u; float f; } cv; cv.u = ((uint)h) << 16; return cv.f;
}
__device__ __forceinline__ ushort f2b(float f) {
    union { float f; uint u; } cv; cv.f = f;
    return (ushort)((cv.u + 0x7FFF + ((cv.u >> 16) & 1)) >> 16);
}
__device__ __forceinline__ ushort f2b_fast(float f) {   // round-half-up, 2 ops
    union { float f; uint u; } cv; cv.f = f;
    return (ushort)((cv.u + 0x8000) >> 16);
}
// pack two f32 -> packed bf16 pair (round-half-up) with one v_perm_b32
__device__ __forceinline__ uint pack_bf16(float a, float b) {
    union { float f; uint u; } ua, ub; ua.f = a; ub.f = b;
    return __builtin_amdgcn_perm(ub.u + 0x8000u, ua.u + 0x8000u, 0x07060302u);
}
__device__ __forceinline__ void gl2lds16(const ushort* g, ushort* l) {
    __builtin_amdgcn_global_load_lds(
        (const __attribute__((address_space(1))) void*)g,
        (__attribute__((address_space(3))) void*)l, 16, 0, 0);
}

// ---------------------------------------------------------------------------
// prep. Extended-B (wqkvb) is now PACKED to 3072 rows: q/k main keep only
// d<56 (16 heads x 56 = 896 rows each), v full (1024), q_low/k_low (256).
// This removes the 256 dead columns gemm_qkv used to compute and discard.
//   blocks [0,32)      : Wlow -> wqkvb rows 2816+
//   blocks [32,48)     : bias_pre[h][t] = w_disc[h]*log2e*d_bias[h][t]
//   blocks [48,7984)   : bulk converts (x 4096 | wqkvb-gather 2816 | wproj 1024)
// ---------------------------------------------------------------------------
__global__ __launch_bounds__(256) void prep_kernel(
    const float* __restrict__ x, const float* __restrict__ Wqkv,
    const float* __restrict__ Wproj, const float* __restrict__ W_recip,
    const float* __restrict__ w_disc, const float* __restrict__ d_bias,
    ushort* __restrict__ xb, ushort* __restrict__ wqkvb,
    ushort* __restrict__ wprojb, float* __restrict__ bias_pre)
{
    const int bid = blockIdx.x;
    if (bid >= 48) {
        const int off0 = bid - 48;
        const int e = threadIdx.x * 4;
        if (off0 < 4096) {                       // xb: row = off0
            const float4 v = *(const float4*)&x[(size_t)off0 * 1024 + e];
            ushort4 o;
            o.x = f2b(v.x); o.y = f2b(v.y); o.z = f2b(v.z); o.w = f2b(v.w);
            *(ushort4*)&xb[(size_t)off0 * 1024 + e] = o;
        } else if (off0 < 6912) {                // wqkvb packed rows 0..2815
            const int r = off0 - 4096;
            int src_row;
            if (r < 1792) {                      // q/k main, 56-dim heads
                const int qk = (r >= 896) ? 1 : 0;
                const int rr = r - qk * 896;
                const int h = rr / 56;
                const int d = rr - h * 56;
                src_row = qk * 1024 + h * 64 + d;
            } else {                             // v, full 64-dim
                src_row = 2048 + (r - 1792);
            }
            const float4 v = *(const float4*)&Wqkv[(size_t)src_row * 1024 + e];
            ushort4 o;
            o.x = f2b(v.x); o.y = f2b(v.y); o.z = f2b(v.z); o.w = f2b(v.w);
            *(ushort4*)&wqkvb[(size_t)r * 1024 + e] = o;
        } else {                                 // wproj: row = off0-6912
            const int r = off0 - 6912;
            const float4 v = *(const float4*)&Wproj[(size_t)r * 1024 + e];
            ushort4 o;
            o.x = f2b(v.x); o.y = f2b(v.y); o.z = f2b(v.z); o.w = f2b(v.w);
            *(ushort4*)&wprojb[(size_t)r * 1024 + e] = o;
        }
        return;
    }
    if (bid >= 32) {
        const int h = bid - 32;
        const float wd = w_disc[h] * LOG2E;
        const int j = h * T_SEQ + threadIdx.x * 8;
        const float4 a = *(const float4*)&d_bias[j];
        const float4 c = *(const float4*)&d_bias[j + 4];
        float4 oa, oc;
        oa.x = a.x * wd; oa.y = a.y * wd; oa.z = a.z * wd; oa.w = a.w * wd;
        oc.x = c.x * wd; oc.y = c.y * wd; oc.z = c.z * wd; oc.w = c.w * wd;
        *(float4*)&bias_pre[j] = oa;
        *(float4*)&bias_pre[j + 4] = oc;
        return;
    }
    const int qk = bid >> 4, h = bid & 15;
    const int e0 = threadIdx.x * 4;
    f32x4 acc[8];
    #pragma unroll
    for (int r = 0; r < 8; ++r) acc[r] = (f32x4){0.f, 0.f, 0.f, 0.f};
    #pragma unroll 4
    for (int d = 0; d < 64; ++d) {
        const float4 xv = *(const float4*)&Wqkv[(size_t)(qk * 1024 + h * 64 + d) * 1024 + e0];
        #pragma unroll
        for (int r = 0; r < 8; ++r) {
            const float w = W_recip[d * 8 + r];
            acc[r][0] = fmaf(w, xv.x, acc[r][0]);
            acc[r][1] = fmaf(w, xv.y, acc[r][1]);
            acc[r][2] = fmaf(w, xv.z, acc[r][2]);
            acc[r][3] = fmaf(w, xv.w, acc[r][3]);
        }
    }
    #pragma unroll
    for (int r = 0; r < 8; ++r) {
        ushort4 o;
        o.x = f2b(acc[r][0]); o.y = f2b(acc[r][1]);
        o.z = f2b(acc[r][2]); o.w = f2b(acc[r][3]);
        *(ushort4*)&wqkvb[(size_t)(2816 + qk * 128 + h * 8 + r) * 1024 + e0] = o;
    }
}

// ---------------------------------------------------------------------------
// bf16 MFMA GEMM core (128x128 tile, BK=64, 4 waves, global_load_lds staging,
// XOR-swizzled LDS both sides).
// ---------------------------------------------------------------------------
#define GEMM_CORE(Aptr, Bptr, KDIM, SMEMN)                                     \
    __shared__ __align__(16) ushort SMEM[SMEMN];                               \
    ushort* const Asl = SMEM;                                                  \
    ushort* const Bsl = SMEM + 8192;                                           \
    const int row0 = blockIdx.x * 128;                                         \
    const int col0 = blockIdx.y * 128;                                         \
    const int tid = threadIdx.x;                                               \
    const int wave = tid >> 6, lane = tid & 63;                                \
    const int wm = wave >> 1, wn = wave & 1;                                   \
    const int quad = lane >> 4, lq = lane & 15;                                \
    const int l7 = lq & 7;                                                     \
    f32x4 acc[4][4];                                                           \
    _Pragma("unroll") for (int i = 0; i < 4; ++i)                              \
        _Pragma("unroll") for (int j = 0; j < 4; ++j)                          \
            acc[i][j] = (f32x4){0.f, 0.f, 0.f, 0.f};                           \
    for (int k0 = 0; k0 < (KDIM); k0 += 64) {                                  \
        _Pragma("unroll") for (int p = 0; p < 4; ++p) {                        \
            const int idx = p * 256 + tid;                                     \
            const int row = idx >> 3, slot = idx & 7;                          \
            const int kc = (slot ^ (row & 7)) << 3;                            \
            gl2lds16(&(Aptr)[(size_t)(row0 + row) * (KDIM) + k0 + kc], &Asl[idx * 8]); \
            gl2lds16(&(Bptr)[(size_t)(col0 + row) * (KDIM) + k0 + kc], &Bsl[idx * 8]); \
        }                                                                      \
        __syncthreads();                                                       \
        _Pragma("unroll") for (int ks = 0; ks < 2; ++ks) {                     \
            short8 af[4], bf[4];                                               \
            _Pragma("unroll") for (int i = 0; i < 4; ++i)                      \
                af[i] = *(const short8*)&Asl[(wm * 64 + i * 16 + lq) * 64 +    \
                                             (((ks * 4 + quad) ^ l7) << 3)];   \
            _Pragma("unroll") for (int j = 0; j < 4; ++j)                      \
                bf[j] = *(const short8*)&Bsl[(wn * 64 + j * 16 + lq) * 64 +    \
                                             (((ks * 4 + quad) ^ l7) << 3)];   \
            _Pragma("unroll") for (int i = 0; i < 4; ++i)                      \
                _Pragma("unroll") for (int j = 0; j < 4; ++j)                  \
                    acc[i][j] = __builtin_amdgcn_mfma_f32_16x16x32_bf16(       \
                        af[i], bf[j], acc[i][j], 0, 0, 0);                     \
        }                                                                      \
        __syncthreads();                                                       \
    }

// Kernel 1: extended qkv GEMM, N=3072 (packed: no dead q/k d=56..63 cols).
// Regions: [0,896) q main | [896,1792) k main | [1792,2816) v |
//          [2816,2944) q_low -> kh tails | [2944,3072) k_low -> qh tails.
// Epilogue Cs stride = 144 ushort (bank-conflict-free quad-row stores).
#define CSTR 144
__global__ __launch_bounds__(256, 4) void gemm_qkv_kernel(
    const ushort* __restrict__ A, const ushort* __restrict__ Bt,
    const float* __restrict__ w_std, const float* __restrict__ w_rec,
    ushort* __restrict__ qh, ushort* __restrict__ kh, ushort* __restrict__ vt)
{
    GEMM_CORE(A, Bt, 1024, 128 * CSTR)
    ushort* const Cs = SMEM;   // epilogue staging, overlays Asl/Bsl (safe)

    if (col0 >= 1792 && col0 < 2816) {
        // V region: vt[b][h][d][t], 4 consecutive t -> packed ushort4 store
        #pragma unroll
        for (int j = 0; j < 4; ++j) {
            const int cc = (col0 - 1792) + wn * 64 + j * 16 + lq;
            const int h = (cc >> 6) & 15;
            const int d = cc & 63;
            #pragma unroll
            for (int i = 0; i < 4; ++i) {
                const int rr0 = row0 + wm * 64 + i * 16 + quad * 4;
                const int b = rr0 >> 11, t0 = rr0 & 2047;
                ushort4 pv;
                pv.x = f2b(acc[i][j][0]); pv.y = f2b(acc[i][j][1]);
                pv.z = f2b(acc[i][j][2]); pv.w = f2b(acc[i][j][3]);
                *(ushort4*)&vt[((((size_t)b * NH + h) * HD + d) * T_SEQ + t0)] = pv;
            }
        }
    } else if (col0 < 1792) {
        // Q/K main, packed 56-dim heads: h = cidx/56, d = cidx%56 (8-aligned
        // chunks never straddle heads since 56 % 8 == 0).
        const bool isq = (col0 < 896);
        const int cbase = col0 - (isq ? 0 : 896);
        #pragma unroll
        for (int j = 0; j < 4; ++j) {
            const int colc = wn * 64 + j * 16 + lq;
            const int h = (cbase + colc) / 56;
            const float sc = isq ? w_std[h] * (0.125f * LOG2E) : 1.0f;
            #pragma unroll
            for (int i = 0; i < 4; ++i)
                #pragma unroll
                for (int r = 0; r < 4; ++r)
                    Cs[(wm * 64 + i * 16 + quad * 4 + r) * CSTR + colc] =
                        f2b(acc[i][j][r] * sc);
        }
        __syncthreads();
        ushort* dst = isq ? qh : kh;
        #pragma unroll
        for (int rep = 0; rep < 8; ++rep) {
            const int id = rep * 256 + tid;
            const int row = id >> 4, chunk = id & 15;
            const int gidx = cbase + chunk * 8;
            const int h = gidx / 56;
            const int d = gidx - h * 56;
            const int rr = row0 + row;
            const int b = rr >> 11, t = rr & 2047;
            const uint4 val = *(const uint4*)&Cs[row * CSTR + chunk * 8];
            *(uint4*)&dst[((((size_t)b * NH + h) * T_SEQ + t) * HD + d)] = val;
        }
    } else {
        // Tails: q_low (col0==2816) -> kh d>=56 (unscaled);
        //        k_low (col0==2944) -> qh d>=56 (w_rec*0.125*log2e)
        const bool isqlow = (col0 < 2944);
        #pragma unroll
        for (int j = 0; j < 4; ++j) {
            const int colc = wn * 64 + j * 16 + lq;
            const int h = colc >> 3;
            const float sc = isqlow ? 1.0f : w_rec[h] * (0.125f * LOG2E);
            #pragma unroll
            for (int i = 0; i < 4; ++i)
                #pragma unroll
                for (int r = 0; r < 4; ++r)
                    Cs[(wm * 64 + i * 16 + quad * 4 + r) * CSTR + colc] =
                        f2b(acc[i][j][r] * sc);
        }
        __syncthreads();
        ushort* dst = isqlow ? kh : qh;
        #pragma unroll
        for (int rep = 0; rep < 8; ++rep) {
            const int id = rep * 256 + tid;
            const int row = id >> 4, h = id & 15;
            const int rr = row0 + row;
            const int b = rr >> 11, t = rr & 2047;
            const uint4 val = *(const uint4*)&Cs[row * CSTR + h * 8];
            *(uint4*)&dst[((((size_t)b * NH + h) * T_SEQ + t) * HD + 56)] = val;
        }
    }
}

// ---------------------------------------------------------------------------
// Kernel 4: out(f32) = ao @ Wproj^T — 128x64 tiles, 512 blocks = 2/CU.
// ---------------------------------------------------------------------------
__global__ __launch_bounds__(256, 4) void gemm_proj_kernel(
    const ushort* __restrict__ A, const ushort* __restrict__ Bt,
    float* __restrict__ C)
{
    __shared__ __align__(16) ushort SMEM[12288];
    ushort* const Asl = SMEM;            // 128 x 64
    ushort* const Bsl = SMEM + 8192;     // 64 x 64
    const int row0 = blockIdx.x * 128;
    const int col0 = blockIdx.y * 64;
    const int tid = threadIdx.x;
    const int wave = tid >> 6, lane = tid & 63;
    const int quad = lane >> 4, lq = lane & 15;
    const int l7 = lq & 7;
    f32x4 acc[2][4];
    #pragma unroll
    for (int i = 0; i < 2; ++i)
        #pragma unroll
        for (int j = 0; j < 4; ++j)
            acc[i][j] = (f32x4){0.f, 0.f, 0.f, 0.f};

    for (int k0 = 0; k0 < 1024; k0 += 64) {
        #pragma unroll
        for (int p = 0; p < 4; ++p) {
            const int idx = p * 256 + tid;
            const int row = idx >> 3, slot = idx & 7;
            const int kc = (slot ^ (row & 7)) << 3;
            gl2lds16(&A[(size_t)(row0 + row) * 1024 + k0 + kc], &Asl[idx * 8]);
        }
        #pragma unroll
        for (int p = 0; p < 2; ++p) {
            const int idx = p * 256 + tid;
            const int row = idx >> 3, slot = idx & 7;
            const int kc = (slot ^ (row & 7)) << 3;
            gl2lds16(&Bt[(size_t)(col0 + row) * 1024 + k0 + kc], &Bsl[idx * 8]);
        }
        __syncthreads();
        #pragma unroll
        for (int ks = 0; ks < 2; ++ks) {
            short8 af[2], bf[4];
            #pragma unroll
            for (int i = 0; i < 2; ++i)
                af[i] = *(const short8*)&Asl[(wave * 32 + i * 16 + lq) * 64 +
                                             (((ks * 4 + quad) ^ l7) << 3)];
            #pragma unroll
            for (int j = 0; j < 4; ++j)
                bf[j] = *(const short8*)&Bsl[(j * 16 + lq) * 64 +
                                             (((ks * 4 + quad) ^ l7) << 3)];
            #pragma unroll
            for (int i = 0; i < 2; ++i)
                #pragma unroll
                for (int j = 0; j < 4; ++j)
                    acc[i][j] = __builtin_amdgcn_mfma_f32_16x16x32_bf16(
                        af[i], bf[j], acc[i][j], 0, 0, 0);
        }
        __syncthreads();
    }
    #pragma unroll
    for (int i = 0; i < 2; ++i) {
        #pragma unroll
        for (int r = 0; r < 4; ++r) {
            const int rr = row0 + wave * 32 + i * 16 + quad * 4 + r;
            #pragma unroll
            for (int j = 0; j < 4; ++j) {
                const int cc = col0 + j * 16 + lq;
                C[(size_t)rr * 1024 + cc] = acc[i][j][r];
            }
        }
    }
}

// ---------------------------------------------------------------------------
// Kernel 3: MFMA attention — R3/R10 structure + two softmax-VALU cuts:
//  (a) causal mask applied ONLY on each tile's last chunk (interior chunks
//      provably satisfy key < qrow: (nc-1)*128 <= qt*64);
//  (b) row-sum via ones-vector MFMA (osum = mfma(ones, P, osum)) — replaces
//      the 24-add serial lsum chain AND the final cross-lane shuffles
//      (MFMA reduces K internally; all 16 fake-d rows hold the full sum).
//      Denominator now sums the same bf16 P used in the numerator.
// ---------------------------------------------------------------------------
#define TILE_COMPUTE(bq, o4, osum, qrow, NTL, MASK) do {                      \
    f32x4 s4[8];                                                              \
    _Pragma("unroll") for (int nt = 0; nt < (NTL); ++nt)                      \
        s4[nt] = *(const f32x4*)&bias_h[k0 + nt * 16 + quad * 4];             \
    __builtin_amdgcn_s_setprio(1);                                            \
    _Pragma("unroll") for (int ks = 0; ks < 2; ++ks)                          \
        _Pragma("unroll") for (int nt = 0; nt < (NTL); ++nt) {                \
            const short8 ak = *(const short8*)                                \
                &Ks[(nt * 16 + lq) * 64 + (((ks * 4 + quad) ^ l7) << 3)];     \
            s4[nt] = __builtin_amdgcn_mfma_f32_16x16x32_bf16(                 \
                ak, (bq)[ks], s4[nt], 0, 0, 0);                               \
        }                                                                     \
    __builtin_amdgcn_s_setprio(0);                                            \
    _Pragma("unroll") for (int nt = 0; nt < (NTL); ++nt) {                    \
        f32x4 sv = s4[nt];                                                    \
        if (MASK) {                                                           \
            const int kb = k0 + nt * 16 + quad * 4;                           \
            _Pragma("unroll") for (int r = 0; r < 4; ++r)                     \
                if (kb + r > (qrow)) sv[r] = NEGINF;                          \
        }                                                                     \
        const float p0 = EXP2(sv[0]), p1 = EXP2(sv[1]);                       \
        const float p2 = EXP2(sv[2]), p3 = EXP2(sv[3]);                       \
        const int pcol = (nt * 16 + quad * 4) ^ (l7 << 3);                    \
        uint2 pv; pv.x = pack_bf16(p0, p1); pv.y = pack_bf16(p2, p3);         \
        *(uint2*)&Ps[prow + pcol] = pv;                                       \
    }                                                                         \
    __builtin_amdgcn_s_setprio(1);                                            \
    _Pragma("unroll") for (int ks = 0; ks < (NTL) / 2; ++ks) {                \
        const short8 bp = *(const short8*)                                    \
            &Ps[prow + ((ks * 32 + quad * 8) ^ (l7 << 3))];                   \
        _Pragma("unroll") for (int dt = 0; dt < 4; ++dt) {                    \
            const short8 bv = *(const short8*)                                \
                &Vs[(dt * 16 + lq) * 128 + (((ks * 4 + quad) ^ lq) << 3)];    \
            (o4)[dt] = __builtin_amdgcn_mfma_f32_16x16x32_bf16(               \
                bv, bp, (o4)[dt], 0, 0, 0);                                   \
        }                                                                     \
        (osum) = __builtin_amdgcn_mfma_f32_16x16x32_bf16(                     \
            vones, bp, (osum), 0, 0, 0);                                      \
    }                                                                         \
    __builtin_amdgcn_s_setprio(0);                                            \
} while (0)

__global__ __launch_bounds__(256, 2) void attn_kernel(
    const ushort* __restrict__ qa, const ushort* __restrict__ ka,
    const ushort* __restrict__ vt, const float* __restrict__ bias_pre,
    ushort* __restrict__ out)
{
    __shared__ __align__(16) ushort Qs[2 * 64 * 64];   // 16 KiB (tiles A,B)
    __shared__ __align__(16) ushort Ks[128 * 64];      // 16 KiB
    __shared__ __align__(16) ushort Ps[64 * 128];      // 16 KiB (shared seq.)
    __shared__ __align__(16) ushort Vs[64 * 128];      // 16 KiB
    const int bh = blockIdx.x;
    const int qtA = blockIdx.y;        // light tile (0..15)
    const int qtB = 31 - blockIdx.y;   // heavy tile (16..31)
    const int h = bh & 15, b = bh >> 4;
    const int tid = threadIdx.x;
    const int wave = tid >> 6, lane = tid & 63;
    const int quad = lane >> 4, lq = lane & 15;
    const int l7 = lq & 7;
    const size_t base = (size_t)bh * T_SEQ * HD;

    short8 vones;
    #pragma unroll
    for (int i = 0; i < 8; ++i) vones[i] = (short)0x3F80;   // bf16 1.0

    // Q stage for both tiles (once), swizzled source -> linear LDS
    #pragma unroll
    for (int rep = 0; rep < 2; ++rep) {
        const int idx = rep * 256 + tid;
        const int row = idx >> 3, slot = idx & 7;
        const int kc = (slot ^ (row & 7)) << 3;
        gl2lds16(&qa[base + (size_t)(qtA * 64 + row) * 64 + kc], &Qs[idx * 8]);
        gl2lds16(&qa[base + (size_t)(qtB * 64 + row) * 64 + kc], &Qs[4096 + idx * 8]);
    }
    __syncthreads();
    short8 bqA[2], bqB[2];
    #pragma unroll
    for (int ks = 0; ks < 2; ++ks) {
        const int off = (wave * 16 + lq) * 64 + (((ks * 4 + quad) ^ l7) << 3);
        bqA[ks] = *(const short8*)&Qs[off];
        bqB[ks] = *(const short8*)&Qs[4096 + off];
    }

    f32x4 o4A[4], o4B[4];
    f32x4 osumA = (f32x4){0.f, 0.f, 0.f, 0.f};
    f32x4 osumB = (f32x4){0.f, 0.f, 0.f, 0.f};
    #pragma unroll
    for (int dt = 0; dt < 4; ++dt) {
        o4A[dt] = (f32x4){0.f, 0.f, 0.f, 0.f};
        o4B[dt] = (f32x4){0.f, 0.f, 0.f, 0.f};
    }
    const int qrowA = qtA * 64 + wave * 16 + lq;
    const int qrowB = qtB * 64 + wave * 16 + lq;
    const int prow = (wave * 16 + lq) * 128;
    const int nA = (qtA + 2) >> 1, nB = (qtB + 2) >> 1;
    const float* bias_h = &bias_pre[h * T_SEQ];

    for (int c = 0; c < nB; ++c) {
        const int k0 = c * 128;
        if (c) __syncthreads();   // prev chunk's K/V/P reads done before restage
        #pragma unroll
        for (int rep = 0; rep < 4; ++rep) {
            const int idx = rep * 256 + tid;
            const int row = idx >> 3, slot = idx & 7;
            gl2lds16(&ka[base + (size_t)(k0 + row) * 64 + ((slot ^ (row & 7)) << 3)],
                     &Ks[idx * 8]);
        }
        #pragma unroll
        for (int rep = 0; rep < 4; ++rep) {
            const int idx = rep * 256 + tid;
            const int row = idx >> 4, slot = idx & 15;
            gl2lds16(&vt[base + (size_t)row * T_SEQ + k0 + ((slot ^ (row & 15)) << 3)],
                     &Vs[idx * 8]);
        }
        __syncthreads();

        // heavy tile (always active); mask only on its last chunk
        if (c == nB - 1) {
            if (!(qtB & 1)) TILE_COMPUTE(bqB, o4B, osumB, qrowB, 4, 1);
            else            TILE_COMPUTE(bqB, o4B, osumB, qrowB, 8, 1);
        } else {
            TILE_COMPUTE(bqB, o4B, osumB, qrowB, 8, 0);
        }
        // light tile (reuses Ps; wave-private rows, same-wave order suffices)
        if (c < nA) {
            if (c == nA - 1) {
                if (!(qtA & 1)) TILE_COMPUTE(bqA, o4A, osumA, qrowA, 4, 1);
                else            TILE_COMPUTE(bqA, o4A, osumA, qrowA, 8, 1);
            } else {
                TILE_COMPUTE(bqA, o4A, osumA, qrowA, 8, 0);
            }
        }
    }

    // osum rows (fake-d) all hold the complete row sum -> no shuffles needed
    const float invA = 1.0f / osumA[0];
    const float invB = 1.0f / osumB[0];
    const size_t obaseA = ((size_t)b * T_SEQ + qrowA) * CEMB + h * HD;
    const size_t obaseB = ((size_t)b * T_SEQ + qrowB) * CEMB + h * HD;
    #pragma unroll
    for (int dt = 0; dt < 4; ++dt) {
        ushort4 ov;
        ov.x = f2b_fast(o4A[dt][0] * invA);
        ov.y = f2b_fast(o4A[dt][1] * invA);
        ov.z = f2b_fast(o4A[dt][2] * invA);
        ov.w = f2b_fast(o4A[dt][3] * invA);
        *(ushort4*)&out[obaseA + dt * 16 + quad * 4] = ov;
        ushort4 ow;
        ow.x = f2b_fast(o4B[dt][0] * invB);
        ow.y = f2b_fast(o4B[dt][1] * invB);
        ow.z = f2b_fast(o4B[dt][2] * invB);
        ow.w = f2b_fast(o4B[dt][3] * invB);
        *(ushort4*)&out[obaseB + dt * 16 + quad * 4] = ow;
    }
}

// ---------------------------------------------------------------------------
extern "C" void kernel_launch(void* const* d_in, const int* in_sizes, int n_in,
                              void* d_out, int out_size, void* d_ws, size_t ws_size,
                              hipStream_t stream) {
    const float* x       = (const float*)d_in[0];
    const float* Wqkv    = (const float*)d_in[1];
    const float* Wproj   = (const float*)d_in[2];
    const float* W_recip = (const float*)d_in[3];
    const float* w_std   = (const float*)d_in[4];
    const float* w_rec   = (const float*)d_in[5];
    const float* w_disc  = (const float*)d_in[6];
    const float* d_bias  = (const float*)d_in[7];
    float* out = (float*)d_out;

    const size_t NX = (size_t)4096 * 1024;
    const size_t NWQKVX = (size_t)3072 * 1024;
    const size_t NWPROJ = (size_t)1024 * 1024;
    ushort* xb     = (ushort*)d_ws;
    ushort* wqkvb  = xb + NX;
    ushort* wprojb = wqkvb + NWQKVX;
    ushort* qh     = wprojb + NWPROJ;
    ushort* kh     = qh + NX;
    ushort* vt     = kh + NX;
    ushort* ao     = vt + NX;
    float*  bias_pre = (float*)(ao + NX);   // 16*2048 f32 = 128 KiB

    prep_kernel<<<7984, 256, 0, stream>>>(x, Wqkv, Wproj, W_recip, w_disc, d_bias,
                                          xb, wqkvb, wprojb, bias_pre);
    gemm_qkv_kernel<<<dim3(32, 24), 256, 0, stream>>>(xb, wqkvb, w_std, w_rec, qh, kh, vt);
    attn_kernel<<<dim3(32, 16), 256, 0, stream>>>(qh, kh, vt, bias_pre, ao);
    gemm_proj_kernel<<<dim3(32, 16), 256, 0, stream>>>(ao, wprojb, out);
}